// Round 8
// baseline (136.582 us; speedup 1.0000x reference)
//
#include <hip/hip_runtime.h>
#include <hip/hip_bf16.h>
#include <math.h>

#define BB 256
#define TT 4096

typedef float f4 __attribute__((ext_vector_type(4)));

typedef const __attribute__((address_space(1))) void* as1_t;
typedef __attribute__((address_space(3))) void* as3_t;

__device__ __forceinline__ void gl_lds16(const float* g, const float* l) {
    // async global->LDS, 16B per lane; LDS dest = uniform base + lane*16
    __builtin_amdgcn_global_load_lds((as1_t)g, (as3_t)l, 16, 0, 0);
}

// Cumulative feature offsets per k segment (k=2..10)
__constant__ int SEGF[10] = {0, 3, 9, 19, 34, 55, 83, 119, 164, 219};

// softmax + PARTIAL packed upper-triangle outer-product accumulate:
// only entries idx in [E0,E1) are accumulated (guard folds at compile time).
template <int K, int E0, int E1>
__device__ __forceinline__ void row_update_range(float (&v)[K],
                                                 float (&acc)[E1 - E0]) {
    float m = v[0];
#pragma unroll
    for (int c = 1; c < K; ++c) m = fmaxf(m, v[c]);
    float s = 0.f;
#pragma unroll
    for (int c = 0; c < K; ++c) { v[c] = __expf(v[c] - m); s += v[c]; }
    const float inv = 1.0f / s;
#pragma unroll
    for (int c = 0; c < K; ++c) v[c] *= inv;
#pragma unroll
    for (int i = 0; i < K; ++i) {
#pragma unroll
        for (int j = i; j < K; ++j) {
            const int idx = i * K - (i * (i - 1)) / 2 + (j - i);
            if (idx >= E0 && idx < E1)
                acc[idx - E0] = fmaf(v[i], v[j], acc[idx - E0]);
        }
    }
}

// ---------------------------------------------------------------------------
// g_lo: k=2..6, exactly the R4 structure (passed, low reg pressure).
// Block=(b,kidx,ch): 2048 rows; 4 waves x 512 rows. No barriers in main loop.
// ---------------------------------------------------------------------------
template <int K>
__device__ __forceinline__ void g_accum_lo(const float* __restrict__ L,
                                           float* __restrict__ gdst,
                                           float* __restrict__ ldsAll,
                                           float* __restrict__ part, int b,
                                           int ch) {
    constexpr int NACC = K * (K + 1) / 2;
    const int tid = threadIdx.x;
    const int lane = tid & 63;
    const int w = tid >> 6;

    float acc[NACC];
#pragma unroll
    for (int i = 0; i < NACC; ++i) acc[i] = 0.f;

    const float* Lw = L + ((size_t)b * TT + (size_t)ch * 2048 + (size_t)w * 512) * K;

    if constexpr (K == 2 || K == 4) {
        constexpr int RPF = (K == 2) ? 2 : 1;  // rows per lane-iter
        constexpr int TR = 64 * RPF;
        constexpr int NT = 512 / TR;
        f4 cur, nxt;
        cur = *(const f4*)(Lw + (size_t)lane * 4);
#pragma unroll
        for (int t = 0; t < NT; ++t) {
            if (t < NT - 1)
                nxt = *(const f4*)(Lw + (size_t)(t + 1) * TR * K + (size_t)lane * 4);
            if constexpr (K == 2) {
#pragma unroll
                for (int r = 0; r < 2; ++r) {
                    float v[2] = {cur[2 * r], cur[2 * r + 1]};
                    row_update_range<2, 0, 3>(v, acc);
                }
            } else {
                float v[4] = {cur[0], cur[1], cur[2], cur[3]};
                row_update_range<4, 0, 10>(v, acc);
            }
            cur = nxt;
        }
    } else {
        // LDS path: tile = 64 rows = 256*K bytes per wave.
        constexpr int VF = K / 4;
        constexpr int RL = 16 * (K % 4);
        constexpr int VOPS = VF + (RL ? 1 : 0);
        float* bA = ldsAll + w * 2 * 640;
        float* bB = bA + 640;
        {
            const float* src = Lw;
#pragma unroll
            for (int s = 0; s < VF; ++s)
                gl_lds16(src + s * 256 + lane * 4, bA + s * 256);
            if constexpr (RL > 0)
                if (lane < RL) gl_lds16(src + VF * 256 + lane * 4, bA + VF * 256);
        }
#pragma unroll
        for (int t = 0; t < 8; ++t) {
            float* rd = (t & 1) ? bB : bA;
            float* wr = (t & 1) ? bA : bB;
            if (t < 7) {
                const float* src = Lw + (size_t)(t + 1) * 64 * K;
#pragma unroll
                for (int s = 0; s < VF; ++s)
                    gl_lds16(src + s * 256 + lane * 4, wr + s * 256);
                if constexpr (RL > 0)
                    if (lane < RL) gl_lds16(src + VF * 256 + lane * 4, wr + VF * 256);
                __builtin_amdgcn_s_waitcnt(0xF70 | VOPS);
            } else {
                __builtin_amdgcn_s_waitcnt(0xF70);
            }
            __builtin_amdgcn_sched_barrier(0);
            const float* myrow = rd + lane * K;
            float v[K];
#pragma unroll
            for (int c = 0; c < K; ++c) v[c] = myrow[c];
            row_update_range<K, 0, NACC>(v, acc);
        }
    }

#pragma unroll
    for (int i = 0; i < NACC; ++i) {
        float x = acc[i];
#pragma unroll
        for (int off = 32; off > 0; off >>= 1) x += __shfl_down(x, off, 64);
        if (lane == 0) part[w * 55 + i] = x;
    }
    __syncthreads();

    if (tid < NACC) {
        const float x = part[0 * 55 + tid] + part[1 * 55 + tid] +
                        part[2 * 55 + tid] + part[3 * 55 + tid];
        int i = 0, rem = tid;
        while (rem >= K - i) { rem -= K - i; ++i; }
        const int j = i + rem;
        int tgt;
        if (j == i) tgt = i;
        else tgt = K + i * (K - 1) - (i * (i - 1)) / 2 + (j - i - 1);
        gdst[tgt] = x;  // unscaled; head applies 1/T
    }
}

__global__ __launch_bounds__(256, 3) void g_lo_kernel(
    const float* __restrict__ l2, const float* __restrict__ l3,
    const float* __restrict__ l4, const float* __restrict__ l5,
    const float* __restrict__ l6, float* __restrict__ ws) {
    __shared__ float lds[4 * 2 * 640];
    __shared__ float part[4 * 55];
    const int flat = blockIdx.x;  // 5*512 blocks, k=6 first
    const int kslot = flat >> 9;  // 0..4
    const int kidx = 4 - kslot;   // 4 -> k=6 first
    const int idx = flat & 511;
    const int b = idx >> 1;
    const int ch = idx & 1;
    float* gdst = ws + ((size_t)(b * 9 + kidx) * 2 + ch) * 55;
    switch (kidx) {
        case 0: g_accum_lo<2>(l2, gdst, lds, part, b, ch); break;
        case 1: g_accum_lo<3>(l3, gdst, lds, part, b, ch); break;
        case 2: g_accum_lo<4>(l4, gdst, lds, part, b, ch); break;
        case 3: g_accum_lo<5>(l5, gdst, lds, part, b, ch); break;
        case 4: g_accum_lo<6>(l6, gdst, lds, part, b, ch); break;
    }
}

// ---------------------------------------------------------------------------
// g_hi: k=7..10. Entry-split x row-split: wave w = 2p+h; pair p owns 1024
// rows of the 2048-row chunk; half h owns Gram entries [E0,E1) (max 28 ->
// accumulators stay in architected VGPRs, no AGPR/scratch shuffling).
// Pair partners read the same rows (second read hits L2).
// ---------------------------------------------------------------------------
template <int K, int E0, int E1>
__device__ __forceinline__ void g_accum_hi(const float* __restrict__ L,
                                           float* __restrict__ ldsAll,
                                           float* __restrict__ part, int b,
                                           int ch) {
    constexpr int NE = E1 - E0;
    const int tid = threadIdx.x;
    const int lane = tid & 63;
    const int w = tid >> 6;
    const int p = w >> 1;

    float acc[NE];
#pragma unroll
    for (int i = 0; i < NE; ++i) acc[i] = 0.f;

    const float* Lw = L + ((size_t)b * TT + (size_t)ch * 2048 + (size_t)p * 1024) * K;

    if constexpr (K == 8) {
        f4 cur[2], nxt[2];
        {
            const float* q = Lw + (size_t)lane * 8;
            cur[0] = *(const f4*)(q);
            cur[1] = *(const f4*)(q + 4);
        }
#pragma unroll
        for (int t = 0; t < 16; ++t) {
            if (t < 15) {
                const float* q = Lw + (size_t)(t + 1) * 512 + (size_t)lane * 8;
                nxt[0] = *(const f4*)(q);
                nxt[1] = *(const f4*)(q + 4);
            }
            float v[8];
#pragma unroll
            for (int j = 0; j < 4; ++j) {
                v[j] = cur[0][j];
                v[4 + j] = cur[1][j];
            }
            row_update_range<8, E0, E1>(v, acc);
            cur[0] = nxt[0];
            cur[1] = nxt[1];
        }
    } else {
        // LDS path: tile = 64 rows = 256*K bytes per wave, 16 tiles.
        constexpr int VF = K / 4;
        constexpr int RL = 16 * (K % 4);
        constexpr int VOPS = VF + (RL ? 1 : 0);
        float* bA = ldsAll + w * 2 * 640;
        float* bB = bA + 640;
        {
            const float* src = Lw;
#pragma unroll
            for (int s = 0; s < VF; ++s)
                gl_lds16(src + s * 256 + lane * 4, bA + s * 256);
            if constexpr (RL > 0)
                if (lane < RL) gl_lds16(src + VF * 256 + lane * 4, bA + VF * 256);
        }
#pragma unroll
        for (int t = 0; t < 16; ++t) {
            float* rd = (t & 1) ? bB : bA;
            float* wr = (t & 1) ? bA : bB;
            if (t < 15) {
                const float* src = Lw + (size_t)(t + 1) * 64 * K;
#pragma unroll
                for (int s = 0; s < VF; ++s)
                    gl_lds16(src + s * 256 + lane * 4, wr + s * 256);
                if constexpr (RL > 0)
                    if (lane < RL) gl_lds16(src + VF * 256 + lane * 4, wr + VF * 256);
                __builtin_amdgcn_s_waitcnt(0xF70 | VOPS);
            } else {
                __builtin_amdgcn_s_waitcnt(0xF70);
            }
            __builtin_amdgcn_sched_barrier(0);
            const float* myrow = rd + lane * K;
            float v[K];
#pragma unroll
            for (int c = 0; c < K; ++c) v[c] = myrow[c];
            row_update_range<K, E0, E1>(v, acc);
        }
    }

    // wave partial: entries [E0,E1) summed over this pair's 1024 rows
#pragma unroll
    for (int i = 0; i < NE; ++i) {
        float x = acc[i];
#pragma unroll
        for (int off = 32; off > 0; off >>= 1) x += __shfl_down(x, off, 64);
        if (lane == 0) part[w * 55 + E0 + i] = x;
    }
}

template <int K>
__device__ __forceinline__ void g_hi_dispatch(const float* __restrict__ L,
                                              float* __restrict__ gdst,
                                              float* __restrict__ ldsAll,
                                              float* __restrict__ part, int b,
                                              int ch) {
    constexpr int NACC = K * (K + 1) / 2;
    constexpr int H = (NACC + 1) / 2;
    const int tid = threadIdx.x;
    const int h = (tid >> 6) & 1;
    if (h == 0) g_accum_hi<K, 0, H>(L, ldsAll, part, b, ch);
    else        g_accum_hi<K, H, NACC>(L, ldsAll, part, b, ch);
    __syncthreads();

    if (tid < NACC) {
        const int he = (tid >= H) ? 1 : 0;
        const float x = part[he * 55 + tid] + part[(2 + he) * 55 + tid];
        int i = 0, rem = tid;
        while (rem >= K - i) { rem -= K - i; ++i; }
        const int j = i + rem;
        int tgt;
        if (j == i) tgt = i;
        else tgt = K + i * (K - 1) - (i * (i - 1)) / 2 + (j - i - 1);
        gdst[tgt] = x;  // unscaled; head applies 1/T
    }
}

__global__ __launch_bounds__(256, 3) void g_hi_kernel(
    const float* __restrict__ l7, const float* __restrict__ l8,
    const float* __restrict__ l9, const float* __restrict__ l10,
    float* __restrict__ ws) {
    __shared__ float lds[4 * 2 * 640];
    __shared__ float part[4 * 55];
    const int flat = blockIdx.x;  // 4*512 blocks, k=10 first
    const int kslot = flat >> 9;  // 0..3
    const int kidx = 8 - kslot;   // 8 -> k=10 first
    const int idx = flat & 511;
    const int b = idx >> 1;
    const int ch = idx & 1;
    float* gdst = ws + ((size_t)(b * 9 + kidx) * 2 + ch) * 55;
    switch (kidx) {
        case 5: g_hi_dispatch<7>(l7, gdst, lds, part, b, ch); break;
        case 6: g_hi_dispatch<8>(l8, gdst, lds, part, b, ch); break;
        case 7: g_hi_dispatch<9>(l9, gdst, lds, part, b, ch); break;
        case 8: g_hi_dispatch<10>(l10, gdst, lds, part, b, ch); break;
    }
}

// ---------------------------------------------------------------------------
// Kernel B: per batch row — gather partials, rank-sort segments, LayerNorm,
// MLP head. (identical to R4/R7)
// ---------------------------------------------------------------------------
__device__ __forceinline__ float gelu_exact(float x) {
    return 0.5f * x * (1.0f + erff(x * 0.70710678118654752440f));
}

__global__ __launch_bounds__(256) void head_kernel(
    const float* __restrict__ ws, const float* __restrict__ gamma,
    const float* __restrict__ beta, const float* __restrict__ w1,
    const float* __restrict__ b1, const float* __restrict__ w2,
    const float* __restrict__ b2, const float* __restrict__ w3,
    const float* __restrict__ b3, float* __restrict__ out) {
    const int b = blockIdx.x;
    const int tid = threadIdx.x;

    __shared__ float pre[219];
    __shared__ float srt[219];
    __shared__ float xln[219];
    __shared__ float h1[256];
    __shared__ float h2[256];
    __shared__ float rs1[4], rs2[4];
    __shared__ float smu, srv;

    if (tid < 219) {
        int ik = 0;
        while (tid >= SEGF[ik + 1]) ++ik;
        const int local = tid - SEGF[ik];
        const float* p0 = ws + ((size_t)(b * 9 + ik) * 2) * 55;
        pre[tid] = (p0[local] + p0[55 + local]) * (1.0f / (float)TT);
    }
    __syncthreads();

    if (tid < 219) {
        int ik = 0;
        while (tid >= SEGF[ik + 1]) ++ik;
        const int K = ik + 2;
        const int base = SEGF[ik];
        const int local = tid - base;
        int sstart, slen, lidx;
        if (local < K) { sstart = base; slen = K; lidx = local; }
        else { sstart = base + K; slen = (K * (K - 1)) / 2; lidx = local - K; }
        const float v = pre[tid];
        int rank = 0;
        for (int m = 0; m < slen; ++m) {
            const float u = pre[sstart + m];
            rank += (u > v) || ((u == v) && (m < lidx));
        }
        srt[sstart + rank] = v;
    }
    __syncthreads();

    const float val = (tid < 219) ? srt[tid] : 0.f;
    float s1 = val, s2 = val * val;
#pragma unroll
    for (int off = 32; off > 0; off >>= 1) {
        s1 += __shfl_down(s1, off, 64);
        s2 += __shfl_down(s2, off, 64);
    }
    const int wave = tid >> 6, lane = tid & 63;
    if (lane == 0) { rs1[wave] = s1; rs2[wave] = s2; }
    __syncthreads();
    if (tid == 0) {
        const float t1 = rs1[0] + rs1[1] + rs1[2] + rs1[3];
        const float t2 = rs2[0] + rs2[1] + rs2[2] + rs2[3];
        const float mu = t1 * (1.0f / 219.0f);
        const float var = t2 * (1.0f / 219.0f) - mu * mu;
        smu = mu;
        srv = rsqrtf(var + 1e-5f);
    }
    __syncthreads();
    if (tid < 219) xln[tid] = (srt[tid] - smu) * srv * gamma[tid] + beta[tid];
    __syncthreads();

    {
        float a = b1[tid];
#pragma unroll 8
        for (int i = 0; i < 219; ++i) a = fmaf(xln[i], w1[i * 256 + tid], a);
        h1[tid] = gelu_exact(a);
    }
    __syncthreads();

    {
        float c = b2[tid];
#pragma unroll 8
        for (int i = 0; i < 256; ++i) c = fmaf(h1[i], w2[i * 256 + tid], c);
        h2[tid] = gelu_exact(c);
    }
    __syncthreads();

    if (tid < 9) {
        float o = b3[tid];
#pragma unroll 8
        for (int i = 0; i < 256; ++i) o = fmaf(h2[i], w3[i * 9 + tid], o);
        out[(size_t)b * 9 + tid] = o;
    }
}

// ---------------------------------------------------------------------------
extern "C" void kernel_launch(void* const* d_in, const int* in_sizes, int n_in,
                              void* d_out, int out_size, void* d_ws,
                              size_t ws_size, hipStream_t stream) {
    const float* l2 = (const float*)d_in[0];
    const float* l3 = (const float*)d_in[1];
    const float* l4 = (const float*)d_in[2];
    const float* l5 = (const float*)d_in[3];
    const float* l6 = (const float*)d_in[4];
    const float* l7 = (const float*)d_in[5];
    const float* l8 = (const float*)d_in[6];
    const float* l9 = (const float*)d_in[7];
    const float* l10 = (const float*)d_in[8];
    const float* gamma = (const float*)d_in[9];
    const float* beta = (const float*)d_in[10];
    const float* w1 = (const float*)d_in[11];
    const float* b1 = (const float*)d_in[12];
    const float* w2 = (const float*)d_in[13];
    const float* b2 = (const float*)d_in[14];
    const float* w3 = (const float*)d_in[15];
    const float* b3 = (const float*)d_in[16];

    float* wsf = (float*)d_ws;  // [256][9][2][55] floats
    float* outp = (float*)d_out;

    g_hi_kernel<<<4 * 512, 256, 0, stream>>>(l7, l8, l9, l10, wsf);
    g_lo_kernel<<<5 * 512, 256, 0, stream>>>(l2, l3, l4, l5, l6, wsf);
    head_kernel<<<BB, 256, 0, stream>>>(wsf, gamma, beta, w1, b1, w2, b2, w3,
                                        b3, outp);
}